// Round 6
// baseline (258.845 us; speedup 1.0000x reference)
//
#include <hip/hip_runtime.h>
#include <math.h>

#define BB 2
#define LL 2048
#define DMM 512
#define HH 8
#define DD 64
#define NUMK 40
#define NUMQ 40
#define LNEPS 1e-5f
#define LSEG 512
#define NLS 4

typedef unsigned short ushort_t;
typedef __attribute__((ext_vector_type(8))) short bf16x8;
typedef __attribute__((ext_vector_type(4))) float f32x4;

// ---- bf16 helpers (RNE) ----
__device__ inline ushort_t f2bf(float x) {
    union { float f; unsigned int u; } v; v.f = x;
    unsigned int r = v.u + 0x7fffu + ((v.u >> 16) & 1u);
    return (ushort_t)(r >> 16);
}
__device__ inline float bf2f(ushort_t h) {
    union { unsigned int u; float f; } v; v.u = ((unsigned int)h) << 16;
    return v.f;
}

// ---------------- K0a: convert X (q,k,v) -> hi/lo bf16 ----------------------
__global__ __launch_bounds__(256) void convert_x_kernel(
    const float* __restrict__ q, const float* __restrict__ k, const float* __restrict__ v,
    ushort_t* __restrict__ Xh, ushort_t* __restrict__ Xl) {
    const size_t plane = (size_t)BB * LL * DMM;
    const float* X = (blockIdx.y == 0) ? q : (blockIdx.y == 1) ? k : v;
    ushort_t* xh = Xh + plane * blockIdx.y;
    ushort_t* xl = Xl + plane * blockIdx.y;
    const size_t base = ((size_t)blockIdx.x * 256 + threadIdx.x) * 8;
    float4 a = *(const float4*)(X + base);
    float4 b = *(const float4*)(X + base + 4);
    float xs[8] = {a.x, a.y, a.z, a.w, b.x, b.y, b.z, b.w};
    unsigned int hp[4], lp[4];
#pragma unroll
    for (int j = 0; j < 4; ++j) {
        ushort_t h0 = f2bf(xs[2 * j]),     h1 = f2bf(xs[2 * j + 1]);
        ushort_t l0 = f2bf(xs[2 * j] - bf2f(h0));
        ushort_t l1 = f2bf(xs[2 * j + 1] - bf2f(h1));
        hp[j] = (unsigned int)h0 | ((unsigned int)h1 << 16);
        lp[j] = (unsigned int)l0 | ((unsigned int)l1 << 16);
    }
    *(uint4*)(xh + base) = make_uint4(hp[0], hp[1], hp[2], hp[3]);
    *(uint4*)(xl + base) = make_uint4(lp[0], lp[1], lp[2], lp[3]);
}

// ---------------- K0b: convert + transpose W -> Wt[n][k] hi/lo bf16 ---------
__global__ __launch_bounds__(256) void convert_w_kernel(
    const float* __restrict__ Wq, const float* __restrict__ Wk, const float* __restrict__ Wv,
    ushort_t* __restrict__ Wht, ushort_t* __restrict__ Wlt) {
    __shared__ float tile[64][65];
    const size_t plane = (size_t)DMM * DMM;
    const float* W = (blockIdx.z == 0) ? Wq : (blockIdx.z == 1) ? Wk : Wv;
    ushort_t* wht = Wht + plane * blockIdx.z;
    ushort_t* wlt = Wlt + plane * blockIdx.z;
    const int n0 = blockIdx.x * 64, k0 = blockIdx.y * 64;
    const int t = threadIdx.x;
    const int d = t & 63, g = t >> 6;
    for (int rr = g; rr < 64; rr += 4)
        tile[rr][d] = W[(size_t)(k0 + rr) * DMM + n0 + d];
    __syncthreads();
    for (int cc = g; cc < 64; cc += 4) {
        float x = tile[d][cc];            // = W[k0+d][n0+cc]
        ushort_t hi = f2bf(x);
        ushort_t lo = f2bf(x - bf2f(hi));
        wht[(size_t)(n0 + cc) * DMM + k0 + d] = hi;
        wlt[(size_t)(n0 + cc) * DMM + k0 + d] = lo;
    }
}

// ---------------- K1: split-bf16 MFMA projection GEMM (3-term) --------------
__device__ inline void stage_one(const ushort_t* __restrict__ g, ushort_t* lbuf,
                                 int r0, int lane, int k0) {
    const int r = r0 + (lane >> 3);
    const int c = (lane & 7) ^ (r & 7);
    const ushort_t* gp = g + (size_t)r * DMM + k0 + c * 8;
    __builtin_amdgcn_global_load_lds(
        (const __attribute__((address_space(1))) unsigned int*)gp,
        (__attribute__((address_space(3))) unsigned int*)(lbuf + (size_t)r0 * 64),
        16, 0, 0);
}
__device__ inline bf16x8 frag_ld(const ushort_t* buf, int row, int c) {
    const int idx = row * 8 + (c ^ (row & 7));
    return *(const bf16x8*)(buf + idx * 8);
}

__global__ __launch_bounds__(256) void proj_mfma_kernel(
    const ushort_t* __restrict__ Xh, const ushort_t* __restrict__ Xl,
    const ushort_t* __restrict__ Wht, const ushort_t* __restrict__ Wlt,
    const float* __restrict__ bq, const float* __restrict__ bk, const float* __restrict__ bv,
    float* __restrict__ Oq, float* __restrict__ Ok, float* __restrict__ Ov) {
    const int z = blockIdx.z;
    const size_t xplane = (size_t)BB * LL * DMM;
    const size_t wplane = (size_t)DMM * DMM;
    const ushort_t* ah_g = Xh + xplane * z;
    const ushort_t* al_g = Xl + xplane * z;
    const ushort_t* bh_g = Wht + wplane * z;
    const ushort_t* bl_g = Wlt + wplane * z;
    const float* bias = (z == 0) ? bq : (z == 1) ? bk : bv;
    float* Out = (z == 0) ? Oq : (z == 1) ? Ok : Ov;

    __shared__ __align__(16) ushort_t bufAh[64 * 64];
    __shared__ __align__(16) ushort_t bufAl[64 * 64];
    __shared__ __align__(16) ushort_t bufBh[64 * 64];
    __shared__ __align__(16) ushort_t bufBl[64 * 64];

    const int t = threadIdx.x;
    const int lane = t & 63, w = t >> 6;
    const int wm = (w & 1) * 32, wn = (w >> 1) * 32;
    const int m0 = blockIdx.x * 64, j0 = blockIdx.y * 64;

    const ushort_t* A_h = ah_g + (size_t)m0 * DMM;
    const ushort_t* A_l = al_g + (size_t)m0 * DMM;
    const ushort_t* B_h = bh_g + (size_t)j0 * DMM;
    const ushort_t* B_l = bl_g + (size_t)j0 * DMM;

    f32x4 acc[2][2];
#pragma unroll
    for (int i = 0; i < 2; ++i)
#pragma unroll
        for (int j = 0; j < 2; ++j) acc[i][j] = (f32x4){0.f, 0.f, 0.f, 0.f};

    for (int ch = 0; ch < 8; ++ch) {
        const int k0 = ch * 64;
#pragma unroll
        for (int i = 0; i < 2; ++i) {
            const int r0 = (w * 2 + i) * 8;
            stage_one(A_h, bufAh, r0, lane, k0);
            stage_one(A_l, bufAl, r0, lane, k0);
            stage_one(B_h, bufBh, r0, lane, k0);
            stage_one(B_l, bufBl, r0, lane, k0);
        }
        __syncthreads();
#pragma unroll
        for (int ks = 0; ks < 2; ++ks) {
            const int cc = ks * 4 + (lane >> 4);
            bf16x8 fah[2], fal[2], fbh[2], fbl[2];
#pragma unroll
            for (int tm = 0; tm < 2; ++tm) {
                const int row = wm + tm * 16 + (lane & 15);
                fah[tm] = frag_ld(bufAh, row, cc);
                fal[tm] = frag_ld(bufAl, row, cc);
            }
#pragma unroll
            for (int tn = 0; tn < 2; ++tn) {
                const int row = wn + tn * 16 + (lane & 15);
                fbh[tn] = frag_ld(bufBh, row, cc);
                fbl[tn] = frag_ld(bufBl, row, cc);
            }
#pragma unroll
            for (int tm = 0; tm < 2; ++tm)
#pragma unroll
                for (int tn = 0; tn < 2; ++tn) {
                    acc[tm][tn] = __builtin_amdgcn_mfma_f32_16x16x32_bf16(fah[tm], fbh[tn], acc[tm][tn], 0, 0, 0);
                    acc[tm][tn] = __builtin_amdgcn_mfma_f32_16x16x32_bf16(fal[tm], fbh[tn], acc[tm][tn], 0, 0, 0);
                    acc[tm][tn] = __builtin_amdgcn_mfma_f32_16x16x32_bf16(fah[tm], fbl[tn], acc[tm][tn], 0, 0, 0);
                }
        }
        __syncthreads();
    }

#pragma unroll
    for (int tn = 0; tn < 2; ++tn) {
        const int gn = j0 + wn + tn * 16 + (lane & 15);
        const float bvv = bias[gn];
        const int h = gn >> 6, d = gn & 63;
#pragma unroll
        for (int tm = 0; tm < 2; ++tm) {
#pragma unroll
            for (int reg = 0; reg < 4; ++reg) {
                const int gm = m0 + wm + tm * 16 + (lane >> 4) * 4 + reg;
                const int b = gm >> 11, l = gm & (LL - 1);
                Out[(((size_t)(b * HH + h)) * LL + l) * DD + d] = acc[tm][tn][reg] + bvv;
            }
        }
    }
}

// ---------------- K1b: transpose (B,H,L,D) -> (B,H,D,L) ---------------------
__global__ __launch_bounds__(256) void transpose_kernel(const float* __restrict__ src,
                                                        float* __restrict__ dst) {
    __shared__ float tile[64][65];
    const int bh = blockIdx.y;
    const int l0 = blockIdx.x * 64;
    const int d = threadIdx.x & 63;
    const int r0 = threadIdx.x >> 6;
    for (int rr = r0; rr < 64; rr += 4)
        tile[rr][d] = src[((size_t)bh * LL + l0 + rr) * DD + d];
    __syncthreads();
    const int li = threadIdx.x & 63;
    for (int dd = r0; dd < 64; dd += 4)
        dst[((size_t)bh * DD + dd) * LL + l0 + li] = tile[li][dd];
}

// ---------------- K2: measure — 4 queries/wave, 16 lanes each ---------------
__global__ __launch_bounds__(256) void measure_kernel(const float* __restrict__ qp2,
                                                      const float* __restrict__ kp2,
                                                      const int* __restrict__ rnd,
                                                      float* __restrict__ measure) {
    const int t = threadIdx.x;
    const int lane = t & 63;
    const int wv = t >> 6;
    const int g = lane >> 4;
    const int dq = (lane & 15) * 4;
    const int bh = blockIdx.x;
    const int i = blockIdx.y * 16 + wv * 4 + g;
    const float4 qv = *(const float4*)(qp2 + ((size_t)bh * LL + i) * DD + dq);
    const float* kbase = kp2 + (size_t)bh * LL * DD;
    const int* rp = rnd + i * NUMK;
    float mx = -INFINITY, sm = 0.f;
#pragma unroll 8
    for (int j = 0; j < NUMK; ++j) {
        const int row = rp[j];
        const float4 kv = *(const float4*)(kbase + (size_t)row * DD + dq);
        float p = kv.x * qv.x;
        p = fmaf(kv.y, qv.y, p); p = fmaf(kv.z, qv.z, p); p = fmaf(kv.w, qv.w, p);
        p += __shfl_xor(p, 1, 64);
        p += __shfl_xor(p, 2, 64);
        p += __shfl_xor(p, 4, 64);
        p += __shfl_xor(p, 8, 64);
        mx = fmaxf(mx, p);
        sm += p;
    }
    if ((lane & 15) == 0) measure[(size_t)bh * LL + i] = mx - sm * (1.0f / LL);
}

// ---------------- K3: exact top-40 per (b,h), lax.top_k tie semantics -------
__global__ __launch_bounds__(256) void topk_kernel(const float* __restrict__ measure,
                                                   int* __restrict__ q_idx,
                                                   int* __restrict__ sel_pos) {
    __shared__ float ms[LL];
    __shared__ float wvv[4];
    __shared__ int wvi[4];
    const int t = threadIdx.x;
    const int bh = blockIdx.x;
    for (int i = t; i < LL; i += 256) {
        ms[i] = measure[(size_t)bh * LL + i];
        sel_pos[(size_t)bh * LL + i] = -1;
    }
    __syncthreads();
    for (int it = 0; it < NUMQ; ++it) {
        float bv = -INFINITY; int bi = 0x7fffffff;
        for (int i = t; i < LL; i += 256) {
            float v = ms[i];
            if (v > bv) { bv = v; bi = i; }
        }
#pragma unroll
        for (int off = 32; off > 0; off >>= 1) {
            float ov = __shfl_xor(bv, off, 64);
            int   oi = __shfl_xor(bi, off, 64);
            if (ov > bv || (ov == bv && oi < bi)) { bv = ov; bi = oi; }
        }
        if ((t & 63) == 0) { wvv[t >> 6] = bv; wvi[t >> 6] = bi; }
        __syncthreads();
        if (t == 0) {
            float fv = wvv[0]; int fi = wvi[0];
#pragma unroll
            for (int u = 1; u < 4; ++u)
                if (wvv[u] > fv || (wvv[u] == fv && wvi[u] < fi)) { fv = wvv[u]; fi = wvi[u]; }
            q_idx[bh * NUMQ + it] = fi;
            sel_pos[(size_t)bh * LL + fi] = it;
            ms[fi] = -INFINITY;
        }
        __syncthreads();
    }
}

// ---------------- K4a: attn partial — grid (bh, qg, ls) ---------------------
// 4 queries x 512-key segment per block. Writes unnormalized exp (local max)
// into attn_out segment + per-(q,seg) partials (m, s, pv[64]).
__global__ __launch_bounds__(256) void attn_part_kernel(
    const float* __restrict__ qp2, const float* __restrict__ kpt,
    const float* __restrict__ vp2, const int* __restrict__ q_idx,
    float* __restrict__ attn_out, float* __restrict__ part_m,
    float* __restrict__ part_s, float* __restrict__ part_pv) {
    __shared__ float qs[4][DD];
    __shared__ float sc[4][LSEG];
    __shared__ float wred[4][4];
    __shared__ float pvred[16][68];
    const int t = threadIdx.x;
    const int lane = t & 63, w = t >> 6;
    const int bh = blockIdx.x;
    const int qg = blockIdx.y;      // 0..9
    const int ls = blockIdx.z;      // 0..3
    const int l0 = ls * LSEG;
    {
        const int qq = t >> 6, d = t & 63;
        const int qi = q_idx[bh * NUMQ + qg * 4 + qq];
        qs[qq][d] = qp2[((size_t)bh * LL + qi) * DD + d];
    }
    __syncthreads();

    // ---- QK^T over segment: thread t owns keys l0+2t, l0+2t+1 ----
    const float* kbase = kpt + (size_t)bh * DD * LL + l0 + 2 * t;
    float2 acc[4];
#pragma unroll
    for (int qq = 0; qq < 4; ++qq) acc[qq] = make_float2(0.f, 0.f);
    for (int d = 0; d < DD; ++d) {
        const float2 kv = *(const float2*)(kbase + (size_t)d * LL);
#pragma unroll
        for (int qq = 0; qq < 4; ++qq) {
            const float qv = qs[qq][d];
            acc[qq].x = fmaf(qv, kv.x, acc[qq].x);
            acc[qq].y = fmaf(qv, kv.y, acc[qq].y);
        }
    }
    const float scale = 0.125f;
    float mx[4];
#pragma unroll
    for (int qq = 0; qq < 4; ++qq) {
        acc[qq].x *= scale; acc[qq].y *= scale;
        float m = fmaxf(acc[qq].x, acc[qq].y);
#pragma unroll
        for (int off = 32; off > 0; off >>= 1) m = fmaxf(m, __shfl_xor(m, off, 64));
        if (lane == 0) wred[w][qq] = m;
    }
    __syncthreads();
#pragma unroll
    for (int qq = 0; qq < 4; ++qq)
        mx[qq] = fmaxf(fmaxf(wred[0][qq], wred[1][qq]), fmaxf(wred[2][qq], wred[3][qq]));
    __syncthreads();

    float sm[4];
#pragma unroll
    for (int qq = 0; qq < 4; ++qq) {
        acc[qq].x = __expf(acc[qq].x - mx[qq]);
        acc[qq].y = __expf(acc[qq].y - mx[qq]);
        *(float2*)&sc[qq][2 * t] = acc[qq];
        float* arow = attn_out + ((size_t)(bh * NUMQ + qg * 4 + qq)) * LL + l0;
        *(float2*)&arow[2 * t] = acc[qq];
        float s = acc[qq].x + acc[qq].y;
#pragma unroll
        for (int off = 32; off > 0; off >>= 1) s += __shfl_xor(s, off, 64);
        if (lane == 0) wred[w][qq] = s;
    }
    __syncthreads();
#pragma unroll
    for (int qq = 0; qq < 4; ++qq)
        sm[qq] = wred[0][qq] + wred[1][qq] + wred[2][qq] + wred[3][qq];

    if (t < 4) {
        const int row = bh * NUMQ + qg * 4 + t;
        part_m[row * NLS + ls] = mx[t];
        part_s[row * NLS + ls] = sm[t];
    }

    // ---- partial PV over segment ----
    const int lg = t >> 4, dq = (t & 15) * 4;
    float4 pv[4];
#pragma unroll
    for (int qq = 0; qq < 4; ++qq) pv[qq] = make_float4(0.f, 0.f, 0.f, 0.f);
    const float* vbase = vp2 + ((size_t)bh * LL + l0) * DD + dq;
    for (int l = lg; l < LSEG; l += 16) {
        const float4 vv = *(const float4*)(vbase + (size_t)l * DD);
#pragma unroll
        for (int qq = 0; qq < 4; ++qq) {
            const float pr = sc[qq][l];
            pv[qq].x = fmaf(pr, vv.x, pv[qq].x);
            pv[qq].y = fmaf(pr, vv.y, pv[qq].y);
            pv[qq].z = fmaf(pr, vv.z, pv[qq].z);
            pv[qq].w = fmaf(pr, vv.w, pv[qq].w);
        }
    }
#pragma unroll
    for (int qq = 0; qq < 4; ++qq) {
        __syncthreads();
        *(float4*)&pvred[lg][dq] = pv[qq];
        __syncthreads();
        if (t < DD) {
            float s = 0.f;
#pragma unroll
            for (int u = 0; u < 16; ++u) s += pvred[u][t];
            const int row = bh * NUMQ + qg * 4 + qq;
            part_pv[((size_t)row * NLS + ls) * DD + t] = s;
        }
    }
}

// ---------------- K4b: attn finalize — one block per (bh,q) row -------------
__global__ __launch_bounds__(256) void attn_fin_kernel(
    const float* __restrict__ part_m, const float* __restrict__ part_s,
    const float* __restrict__ part_pv, float* __restrict__ attn_out,
    float* __restrict__ out_sel) {
    const int row = blockIdx.x;          // bh*NUMQ + q
    const int t = threadIdx.x;
    float m0 = part_m[row * NLS + 0], m1 = part_m[row * NLS + 1];
    float m2 = part_m[row * NLS + 2], m3 = part_m[row * NLS + 3];
    float M = fmaxf(fmaxf(m0, m1), fmaxf(m2, m3));
    float f[NLS];
    f[0] = __expf(m0 - M); f[1] = __expf(m1 - M);
    f[2] = __expf(m2 - M); f[3] = __expf(m3 - M);
    float T = part_s[row * NLS + 0] * f[0] + part_s[row * NLS + 1] * f[1]
            + part_s[row * NLS + 2] * f[2] + part_s[row * NLS + 3] * f[3];
    const float inv = 1.0f / T;
    float* arow = attn_out + (size_t)row * LL;
    {
        float4 v0 = *(const float4*)&arow[4 * t];
        float4 v1 = *(const float4*)&arow[1024 + 4 * t];
        const float g0 = f[(4 * t) >> 9] * inv;
        const float g1 = f[(1024 + 4 * t) >> 9] * inv;
        v0.x *= g0; v0.y *= g0; v0.z *= g0; v0.w *= g0;
        v1.x *= g1; v1.y *= g1; v1.z *= g1; v1.w *= g1;
        *(float4*)&arow[4 * t] = v0;
        *(float4*)&arow[1024 + 4 * t] = v1;
    }
    if (t < DD) {
        float s = part_pv[((size_t)row * NLS + 0) * DD + t] * f[0]
                + part_pv[((size_t)row * NLS + 1) * DD + t] * f[1]
                + part_pv[((size_t)row * NLS + 2) * DD + t] * f[2]
                + part_pv[((size_t)row * NLS + 3) * DD + t] * f[3];
        out_sel[(size_t)row * DD + t] = s * inv;
    }
}

// ---------------- K5: v_mean, two-stage ------------------------------------
__global__ __launch_bounds__(256) void vmean1_kernel(const float* __restrict__ vp2,
                                                     float* __restrict__ partial) {
    __shared__ float pv[256];
    const int t = threadIdx.x;
    const int chunk = blockIdx.x & 31;
    const int bh = blockIdx.x >> 5;
    const int d = t & 63, g = t >> 6;
    const int l0 = chunk * 64;
    float acc = 0.f;
    for (int l = l0 + g; l < l0 + 64; l += 4)
        acc += vp2[((size_t)bh * LL + l) * DD + d];
    pv[t] = acc;
    __syncthreads();
    if (t < 64)
        partial[(size_t)blockIdx.x * 64 + t] = pv[t] + pv[64 + t] + pv[128 + t] + pv[192 + t];
}

__global__ __launch_bounds__(64) void vmean2_kernel(const float* __restrict__ partial,
                                                    float* __restrict__ v_mean) {
    const int bh = blockIdx.x;
    const int t = threadIdx.x;
    float s = 0.f;
    for (int c = 0; c < 32; ++c)
        s += partial[((size_t)bh * 32 + c) * 64 + t];
    v_mean[bh * 64 + t] = s * (1.0f / LL);
}

// ---------------- K6: scatter + residual + LayerNorm ------------------------
__global__ __launch_bounds__(512) void final_kernel(const float* __restrict__ q_in,
                                                    const int* __restrict__ sel_pos,
                                                    const float* __restrict__ out_sel,
                                                    const float* __restrict__ v_mean,
                                                    const float* __restrict__ gamma,
                                                    const float* __restrict__ beta,
                                                    float* __restrict__ yout) {
    __shared__ float wred[8];
    const int j = threadIdx.x;
    const int lane = j & 63, wv = j >> 6;
    const int tok = blockIdx.x;          // b*L + l
    const int b = tok >> 11;
    const int l = tok & (LL - 1);
    const int h = wv, d = lane;
    const int bh = b * HH + h;
    const int p = sel_pos[(size_t)bh * LL + l];
    float val = (p >= 0) ? out_sel[((size_t)bh * NUMQ + p) * DD + d]
                         : v_mean[bh * DD + d];
    float y = val + q_in[(size_t)tok * DMM + j];
    float s = y;
#pragma unroll
    for (int off = 32; off > 0; off >>= 1) s += __shfl_xor(s, off, 64);
    if (lane == 0) wred[wv] = s;
    __syncthreads();
    float tot = 0.f;
#pragma unroll
    for (int u = 0; u < 8; ++u) tot += wred[u];
    float mu = tot * (1.0f / DMM);
    __syncthreads();
    float dv = y - mu;
    float s2 = dv * dv;
#pragma unroll
    for (int off = 32; off > 0; off >>= 1) s2 += __shfl_xor(s2, off, 64);
    if (lane == 0) wred[wv] = s2;
    __syncthreads();
    float tot2 = 0.f;
#pragma unroll
    for (int u = 0; u < 8; ++u) tot2 += wred[u];
    float var = tot2 * (1.0f / DMM);
    float yn = dv * rsqrtf(var + LNEPS) * gamma[j] + beta[j];
    yout[(size_t)tok * DMM + j] = yn;
}

extern "C" void kernel_launch(void* const* d_in, const int* in_sizes, int n_in,
                              void* d_out, int out_size, void* d_ws, size_t ws_size,
                              hipStream_t stream) {
    const float* q     = (const float*)d_in[0];
    const float* k     = (const float*)d_in[1];
    const float* v     = (const float*)d_in[2];
    const float* Wq    = (const float*)d_in[3];
    const float* bq    = (const float*)d_in[4];
    const float* Wk    = (const float*)d_in[5];
    const float* bk    = (const float*)d_in[6];
    const float* Wv    = (const float*)d_in[7];
    const float* bv    = (const float*)d_in[8];
    const float* gamma = (const float*)d_in[9];
    const float* beta  = (const float*)d_in[10];
    const int*   rnd   = (const int*)d_in[11];

    float* ws = (float*)d_ws;
    const size_t proj_sz = (size_t)BB * HH * LL * DD;      // = B*L*DM elements
    float* qp2     = ws;
    float* kp2     = qp2 + proj_sz;
    float* vp2     = kp2 + proj_sz;
    float* kpt     = vp2 + proj_sz;
    float* measure = kpt + proj_sz;                        // B*H*L
    float* out_sel = measure + (size_t)BB * HH * LL;       // B*H*NUMQ*D
    float* v_mean  = out_sel + (size_t)BB * HH * NUMQ * DD;// B*H*D
    float* partial = v_mean + (size_t)BB * HH * DD;        // B*H*32*64
    float* part_m  = partial + (size_t)BB * HH * 32 * 64;  // 640*4
    float* part_s  = part_m + (size_t)BB * HH * NUMQ * NLS;
    float* part_pv = part_s + (size_t)BB * HH * NUMQ * NLS;// 640*4*64
    int*   q_idx   = (int*)(part_pv + (size_t)BB * HH * NUMQ * NLS * DD);
    int*   sel_pos = q_idx + BB * HH * NUMQ;               // B*H*L
    ushort_t* Xh  = (ushort_t*)(sel_pos + BB * HH * LL);
    ushort_t* Xl  = Xh + 3 * proj_sz;
    ushort_t* Wht = Xl + 3 * proj_sz;
    ushort_t* Wlt = Wht + 3 * (size_t)DMM * DMM;

    float* yn_out   = (float*)d_out;
    float* attn_out = yn_out + (size_t)BB * LL * DMM;

    convert_x_kernel<<<dim3(BB * LL * DMM / (256 * 8), 3), 256, 0, stream>>>(q, k, v, Xh, Xl);
    convert_w_kernel<<<dim3(DMM / 64, DMM / 64, 3), 256, 0, stream>>>(Wq, Wk, Wv, Wht, Wlt);
    proj_mfma_kernel<<<dim3(BB * LL / 64, DMM / 64, 3), 256, 0, stream>>>(
        Xh, Xl, Wht, Wlt, bq, bk, bv, qp2, kp2, vp2);
    transpose_kernel<<<dim3(LL / 64, BB * HH), 256, 0, stream>>>(kp2, kpt);
    vmean1_kernel<<<BB * HH * 32, 256, 0, stream>>>(vp2, partial);
    vmean2_kernel<<<BB * HH, 64, 0, stream>>>(partial, v_mean);
    measure_kernel<<<dim3(BB * HH, LL / 16), 256, 0, stream>>>(qp2, kp2, rnd, measure);
    topk_kernel<<<BB * HH, 256, 0, stream>>>(measure, q_idx, sel_pos);
    attn_part_kernel<<<dim3(BB * HH, NUMQ / 4, NLS), 256, 0, stream>>>(
        qp2, kpt, vp2, q_idx, attn_out, part_m, part_s, part_pv);
    attn_fin_kernel<<<BB * HH * NUMQ, 256, 0, stream>>>(
        part_m, part_s, part_pv, attn_out, out_sel);
    final_kernel<<<BB * LL, 512, 0, stream>>>(q, sel_pos, out_sel, v_mean, gamma, beta, yn_out);
}

// Round 7
// 226.883 us; speedup vs baseline: 1.1409x; 1.1409x over previous
//
#include <hip/hip_runtime.h>
#include <math.h>

#define BB 2
#define LL 2048
#define DMM 512
#define HH 8
#define DD 64
#define NUMK 40
#define NUMQ 40
#define LNEPS 1e-5f
#define LSEG 512
#define NLS 4

typedef unsigned short ushort_t;
typedef __attribute__((ext_vector_type(8))) short bf16x8;
typedef __attribute__((ext_vector_type(4))) float f32x4;

// ---- bf16 helpers (RNE) ----
__device__ inline ushort_t f2bf(float x) {
    union { float f; unsigned int u; } v; v.f = x;
    unsigned int r = v.u + 0x7fffu + ((v.u >> 16) & 1u);
    return (ushort_t)(r >> 16);
}
__device__ inline float bf2f(ushort_t h) {
    union { unsigned int u; float f; } v; v.u = ((unsigned int)h) << 16;
    return v.f;
}

// ---------------- K0a: convert X (q,k,v) -> hi/lo bf16 ----------------------
__global__ __launch_bounds__(256) void convert_x_kernel(
    const float* __restrict__ q, const float* __restrict__ k, const float* __restrict__ v,
    ushort_t* __restrict__ Xh, ushort_t* __restrict__ Xl) {
    const size_t plane = (size_t)BB * LL * DMM;
    const float* X = (blockIdx.y == 0) ? q : (blockIdx.y == 1) ? k : v;
    ushort_t* xh = Xh + plane * blockIdx.y;
    ushort_t* xl = Xl + plane * blockIdx.y;
    const size_t base = ((size_t)blockIdx.x * 256 + threadIdx.x) * 8;
    float4 a = *(const float4*)(X + base);
    float4 b = *(const float4*)(X + base + 4);
    float xs[8] = {a.x, a.y, a.z, a.w, b.x, b.y, b.z, b.w};
    unsigned int hp[4], lp[4];
#pragma unroll
    for (int j = 0; j < 4; ++j) {
        ushort_t h0 = f2bf(xs[2 * j]),     h1 = f2bf(xs[2 * j + 1]);
        ushort_t l0 = f2bf(xs[2 * j] - bf2f(h0));
        ushort_t l1 = f2bf(xs[2 * j + 1] - bf2f(h1));
        hp[j] = (unsigned int)h0 | ((unsigned int)h1 << 16);
        lp[j] = (unsigned int)l0 | ((unsigned int)l1 << 16);
    }
    *(uint4*)(xh + base) = make_uint4(hp[0], hp[1], hp[2], hp[3]);
    *(uint4*)(xl + base) = make_uint4(lp[0], lp[1], lp[2], lp[3]);
}

// ---------------- K0b: convert + transpose W -> Wt[n][k] hi/lo bf16 ---------
__global__ __launch_bounds__(256) void convert_w_kernel(
    const float* __restrict__ Wq, const float* __restrict__ Wk, const float* __restrict__ Wv,
    ushort_t* __restrict__ Wht, ushort_t* __restrict__ Wlt) {
    __shared__ float tile[64][65];
    const size_t plane = (size_t)DMM * DMM;
    const float* W = (blockIdx.z == 0) ? Wq : (blockIdx.z == 1) ? Wk : Wv;
    ushort_t* wht = Wht + plane * blockIdx.z;
    ushort_t* wlt = Wlt + plane * blockIdx.z;
    const int n0 = blockIdx.x * 64, k0 = blockIdx.y * 64;
    const int t = threadIdx.x;
    const int d = t & 63, g = t >> 6;
    for (int rr = g; rr < 64; rr += 4)
        tile[rr][d] = W[(size_t)(k0 + rr) * DMM + n0 + d];
    __syncthreads();
    for (int cc = g; cc < 64; cc += 4) {
        float x = tile[d][cc];            // = W[k0+d][n0+cc]
        ushort_t hi = f2bf(x);
        ushort_t lo = f2bf(x - bf2f(hi));
        wht[(size_t)(n0 + cc) * DMM + k0 + d] = hi;
        wlt[(size_t)(n0 + cc) * DMM + k0 + d] = lo;
    }
}

// ---------------- K1: split-bf16 MFMA projection GEMM (3-term) --------------
__device__ inline void stage_one(const ushort_t* __restrict__ g, ushort_t* lbuf,
                                 int r0, int lane, int k0) {
    const int r = r0 + (lane >> 3);
    const int c = (lane & 7) ^ (r & 7);
    const ushort_t* gp = g + (size_t)r * DMM + k0 + c * 8;
    __builtin_amdgcn_global_load_lds(
        (const __attribute__((address_space(1))) unsigned int*)gp,
        (__attribute__((address_space(3))) unsigned int*)(lbuf + (size_t)r0 * 64),
        16, 0, 0);
}
__device__ inline bf16x8 frag_ld(const ushort_t* buf, int row, int c) {
    const int idx = row * 8 + (c ^ (row & 7));
    return *(const bf16x8*)(buf + idx * 8);
}

__global__ __launch_bounds__(256) void proj_mfma_kernel(
    const ushort_t* __restrict__ Xh, const ushort_t* __restrict__ Xl,
    const ushort_t* __restrict__ Wht, const ushort_t* __restrict__ Wlt,
    const float* __restrict__ bq, const float* __restrict__ bk, const float* __restrict__ bv,
    float* __restrict__ Oq, float* __restrict__ Ok, float* __restrict__ Ov) {
    const int z = blockIdx.z;
    const size_t xplane = (size_t)BB * LL * DMM;
    const size_t wplane = (size_t)DMM * DMM;
    const ushort_t* ah_g = Xh + xplane * z;
    const ushort_t* al_g = Xl + xplane * z;
    const ushort_t* bh_g = Wht + wplane * z;
    const ushort_t* bl_g = Wlt + wplane * z;
    const float* bias = (z == 0) ? bq : (z == 1) ? bk : bv;
    float* Out = (z == 0) ? Oq : (z == 1) ? Ok : Ov;

    __shared__ __align__(16) ushort_t bufAh[64 * 64];
    __shared__ __align__(16) ushort_t bufAl[64 * 64];
    __shared__ __align__(16) ushort_t bufBh[64 * 64];
    __shared__ __align__(16) ushort_t bufBl[64 * 64];

    const int t = threadIdx.x;
    const int lane = t & 63, w = t >> 6;
    const int wm = (w & 1) * 32, wn = (w >> 1) * 32;
    const int m0 = blockIdx.x * 64, j0 = blockIdx.y * 64;

    const ushort_t* A_h = ah_g + (size_t)m0 * DMM;
    const ushort_t* A_l = al_g + (size_t)m0 * DMM;
    const ushort_t* B_h = bh_g + (size_t)j0 * DMM;
    const ushort_t* B_l = bl_g + (size_t)j0 * DMM;

    f32x4 acc[2][2];
#pragma unroll
    for (int i = 0; i < 2; ++i)
#pragma unroll
        for (int j = 0; j < 2; ++j) acc[i][j] = (f32x4){0.f, 0.f, 0.f, 0.f};

    for (int ch = 0; ch < 8; ++ch) {
        const int k0 = ch * 64;
#pragma unroll
        for (int i = 0; i < 2; ++i) {
            const int r0 = (w * 2 + i) * 8;
            stage_one(A_h, bufAh, r0, lane, k0);
            stage_one(A_l, bufAl, r0, lane, k0);
            stage_one(B_h, bufBh, r0, lane, k0);
            stage_one(B_l, bufBl, r0, lane, k0);
        }
        __syncthreads();
#pragma unroll
        for (int ks = 0; ks < 2; ++ks) {
            const int cc = ks * 4 + (lane >> 4);
            bf16x8 fah[2], fal[2], fbh[2], fbl[2];
#pragma unroll
            for (int tm = 0; tm < 2; ++tm) {
                const int row = wm + tm * 16 + (lane & 15);
                fah[tm] = frag_ld(bufAh, row, cc);
                fal[tm] = frag_ld(bufAl, row, cc);
            }
#pragma unroll
            for (int tn = 0; tn < 2; ++tn) {
                const int row = wn + tn * 16 + (lane & 15);
                fbh[tn] = frag_ld(bufBh, row, cc);
                fbl[tn] = frag_ld(bufBl, row, cc);
            }
#pragma unroll
            for (int tm = 0; tm < 2; ++tm)
#pragma unroll
                for (int tn = 0; tn < 2; ++tn) {
                    acc[tm][tn] = __builtin_amdgcn_mfma_f32_16x16x32_bf16(fah[tm], fbh[tn], acc[tm][tn], 0, 0, 0);
                    acc[tm][tn] = __builtin_amdgcn_mfma_f32_16x16x32_bf16(fal[tm], fbh[tn], acc[tm][tn], 0, 0, 0);
                    acc[tm][tn] = __builtin_amdgcn_mfma_f32_16x16x32_bf16(fah[tm], fbl[tn], acc[tm][tn], 0, 0, 0);
                }
        }
        __syncthreads();
    }

#pragma unroll
    for (int tn = 0; tn < 2; ++tn) {
        const int gn = j0 + wn + tn * 16 + (lane & 15);
        const float bvv = bias[gn];
        const int h = gn >> 6, d = gn & 63;
#pragma unroll
        for (int tm = 0; tm < 2; ++tm) {
#pragma unroll
            for (int reg = 0; reg < 4; ++reg) {
                const int gm = m0 + wm + tm * 16 + (lane >> 4) * 4 + reg;
                const int b = gm >> 11, l = gm & (LL - 1);
                Out[(((size_t)(b * HH + h)) * LL + l) * DD + d] = acc[tm][tn][reg] + bvv;
            }
        }
    }
}

// ---------------- K2: measure — 4 queries/wave, 16 lanes each ---------------
__global__ __launch_bounds__(256) void measure_kernel(const float* __restrict__ qp2,
                                                      const float* __restrict__ kp2,
                                                      const int* __restrict__ rnd,
                                                      float* __restrict__ measure) {
    const int t = threadIdx.x;
    const int lane = t & 63;
    const int wv = t >> 6;
    const int g = lane >> 4;
    const int dq = (lane & 15) * 4;
    const int bh = blockIdx.x;
    const int i = blockIdx.y * 16 + wv * 4 + g;
    const float4 qv = *(const float4*)(qp2 + ((size_t)bh * LL + i) * DD + dq);
    const float* kbase = kp2 + (size_t)bh * LL * DD;
    const int* rp = rnd + i * NUMK;
    float mx = -INFINITY, sm = 0.f;
#pragma unroll 8
    for (int j = 0; j < NUMK; ++j) {
        const int row = rp[j];
        const float4 kv = *(const float4*)(kbase + (size_t)row * DD + dq);
        float p = kv.x * qv.x;
        p = fmaf(kv.y, qv.y, p); p = fmaf(kv.z, qv.z, p); p = fmaf(kv.w, qv.w, p);
        p += __shfl_xor(p, 1, 64);
        p += __shfl_xor(p, 2, 64);
        p += __shfl_xor(p, 4, 64);
        p += __shfl_xor(p, 8, 64);
        mx = fmaxf(mx, p);
        sm += p;
    }
    if ((lane & 15) == 0) measure[(size_t)bh * LL + i] = mx - sm * (1.0f / LL);
}

// ---------------- K3: exact top-40 per (b,h), lax.top_k tie semantics -------
__global__ __launch_bounds__(256) void topk_kernel(const float* __restrict__ measure,
                                                   int* __restrict__ q_idx,
                                                   int* __restrict__ sel_pos) {
    __shared__ float ms[LL];
    __shared__ float wvv[4];
    __shared__ int wvi[4];
    const int t = threadIdx.x;
    const int bh = blockIdx.x;
    for (int i = t; i < LL; i += 256) {
        ms[i] = measure[(size_t)bh * LL + i];
        sel_pos[(size_t)bh * LL + i] = -1;
    }
    __syncthreads();
    for (int it = 0; it < NUMQ; ++it) {
        float bv = -INFINITY; int bi = 0x7fffffff;
        for (int i = t; i < LL; i += 256) {
            float v = ms[i];
            if (v > bv) { bv = v; bi = i; }
        }
#pragma unroll
        for (int off = 32; off > 0; off >>= 1) {
            float ov = __shfl_xor(bv, off, 64);
            int   oi = __shfl_xor(bi, off, 64);
            if (ov > bv || (ov == bv && oi < bi)) { bv = ov; bi = oi; }
        }
        if ((t & 63) == 0) { wvv[t >> 6] = bv; wvi[t >> 6] = bi; }
        __syncthreads();
        if (t == 0) {
            float fv = wvv[0]; int fi = wvi[0];
#pragma unroll
            for (int u = 1; u < 4; ++u)
                if (wvv[u] > fv || (wvv[u] == fv && wvi[u] < fi)) { fv = wvv[u]; fi = wvi[u]; }
            q_idx[bh * NUMQ + it] = fi;
            sel_pos[(size_t)bh * LL + fi] = it;
            ms[fi] = -INFINITY;
        }
        __syncthreads();
    }
}

// ---------------- K4a: attn partial, LDS-staged -----------------------------
// grid (bh, qg, ls). 4 queries x 512-key segment. K/V streamed through LDS
// in 16KB chunks (64 rows x 64 floats) via global_load_lds, XOR-swizzled
// 16B chunks: logical (row, cg) lives at float idx row*64 + (cg^(row&15))*4.
__global__ __launch_bounds__(256) void attn_part_kernel(
    const float* __restrict__ qp2, const float* __restrict__ kp2,
    const float* __restrict__ vp2, const int* __restrict__ q_idx,
    float* __restrict__ attn_out, float* __restrict__ part_m,
    float* __restrict__ part_s, float* __restrict__ part_pv) {
    __shared__ __align__(16) float buf[2][64 * 64];   // 2 x 16KB
    __shared__ __align__(16) float sc[4][LSEG];       // 8KB
    __shared__ float pvred[16][68];
    const int t = threadIdx.x;
    const int lane = t & 63, w = t >> 6;
    const int bh = blockIdx.x;
    const int qg = blockIdx.y;      // 0..9
    const int ls = blockIdx.z;      // 0..3
    const int l0 = ls * LSEG;
    const int dseg = lane >> 4;     // 0..3: 16-float slice of d
    const int kk = lane & 15;

    // q fragments in registers (pre-scaled by D^-0.5)
    float qrf[4][16];
#pragma unroll
    for (int qq = 0; qq < 4; ++qq) {
        const int qi = q_idx[bh * NUMQ + qg * 4 + qq];
        const float* qrow = qp2 + ((size_t)bh * LL + qi) * DD + dseg * 16;
#pragma unroll
        for (int j = 0; j < 4; ++j) {
            float4 v = *(const float4*)(qrow + j * 4);
            qrf[qq][j * 4 + 0] = v.x * 0.125f;
            qrf[qq][j * 4 + 1] = v.y * 0.125f;
            qrf[qq][j * 4 + 2] = v.z * 0.125f;
            qrf[qq][j * 4 + 3] = v.w * 0.125f;
        }
    }

    const float* kseg = kp2 + ((size_t)bh * LL + l0) * DD;
    const float* vseg = vp2 + ((size_t)bh * LL + l0) * DD;

    // stage one 16KB chunk (64 rows x 256B); wave w issues 4 DMA instrs.
    auto stage = [&](const float* gsrc, float* lb) {
#pragma unroll
        for (int i = 0; i < 4; ++i) {
            const int instr = w * 4 + i;
            const int r = instr * 4 + (lane >> 4);
            const int cg = (lane & 15) ^ (r & 15);
            const float* gp = gsrc + (size_t)r * DD + cg * 4;
            __builtin_amdgcn_global_load_lds(
                (const __attribute__((address_space(1))) unsigned int*)gp,
                (__attribute__((address_space(3))) unsigned int*)(lb + instr * 256),
                16, 0, 0);
        }
    };

    // ---- Loop 1: QK^T ----
    stage(kseg, buf[0]);
    const int krow = w * 16 + kk;          // key row within chunk for this thread
    for (int c = 0; c < 8; ++c) {
        __syncthreads();                   // drains chunk-c DMA
        if (c < 7) stage(kseg + (size_t)(c + 1) * 64 * DD, buf[(c + 1) & 1]);
        const float* lb = buf[c & 1];
        float dot[4] = {0.f, 0.f, 0.f, 0.f};
#pragma unroll
        for (int j = 0; j < 4; ++j) {
            const int cg = dseg * 4 + j;
            const float4 k4 = *(const float4*)(lb + krow * 64 + ((cg ^ (krow & 15)) * 4));
            const float kf[4] = {k4.x, k4.y, k4.z, k4.w};
#pragma unroll
            for (int qq = 0; qq < 4; ++qq)
#pragma unroll
                for (int m = 0; m < 4; ++m)
                    dot[qq] = fmaf(qrf[qq][j * 4 + m], kf[m], dot[qq]);
        }
#pragma unroll
        for (int qq = 0; qq < 4; ++qq) {
            dot[qq] += __shfl_xor(dot[qq], 16, 64);
            dot[qq] += __shfl_xor(dot[qq], 32, 64);
        }
        const float sel = (dseg == 0) ? dot[0] : (dseg == 1) ? dot[1]
                        : (dseg == 2) ? dot[2] : dot[3];
        sc[dseg][c * 64 + krow] = sel;
    }
    // prefetch V chunk 0 (buf[0] last read at c==6, complete before iter-7 barrier)
    stage(vseg, buf[0]);
    __syncthreads();

    // ---- softmax partial: wave w handles query qq = w ----
    const int row = bh * NUMQ + qg * 4 + w;
    {
        float* srow = sc[w];
        float4 v0 = *(float4*)(srow + lane * 8);
        float4 v1 = *(float4*)(srow + lane * 8 + 4);
        float m = fmaxf(fmaxf(fmaxf(v0.x, v0.y), fmaxf(v0.z, v0.w)),
                        fmaxf(fmaxf(v1.x, v1.y), fmaxf(v1.z, v1.w)));
#pragma unroll
        for (int off = 32; off > 0; off >>= 1) m = fmaxf(m, __shfl_xor(m, off, 64));
        v0.x = __expf(v0.x - m); v0.y = __expf(v0.y - m);
        v0.z = __expf(v0.z - m); v0.w = __expf(v0.w - m);
        v1.x = __expf(v1.x - m); v1.y = __expf(v1.y - m);
        v1.z = __expf(v1.z - m); v1.w = __expf(v1.w - m);
        *(float4*)(srow + lane * 8) = v0;
        *(float4*)(srow + lane * 8 + 4) = v1;
        float* arow = attn_out + (size_t)row * LL + l0;
        *(float4*)(arow + lane * 8) = v0;
        *(float4*)(arow + lane * 8 + 4) = v1;
        float s = (v0.x + v0.y + v0.z + v0.w) + (v1.x + v1.y + v1.z + v1.w);
#pragma unroll
        for (int off = 32; off > 0; off >>= 1) s += __shfl_xor(s, off, 64);
        if (lane == 0) {
            part_m[row * NLS + ls] = m;
            part_s[row * NLS + ls] = s;
        }
    }

    // ---- Loop 2: PV ----
    const int dq4 = (t & 15) * 4;     // d offset
    const int grp = t >> 4;           // l-group 0..15 (4 consecutive l each)
    float4 acc[4];
#pragma unroll
    for (int qq = 0; qq < 4; ++qq) acc[qq] = make_float4(0.f, 0.f, 0.f, 0.f);
    for (int c = 0; c < 8; ++c) {
        __syncthreads();               // drains V chunk-c DMA + sc writes (c==0)
        if (c < 7) stage(vseg + (size_t)(c + 1) * 64 * DD, buf[(c + 1) & 1]);
        const float* lb = buf[c & 1];
        float pa[4][4];
#pragma unroll
        for (int qq = 0; qq < 4; ++qq)
            *(float4*)&pa[qq][0] = *(const float4*)&sc[qq][c * 64 + grp * 4];
#pragma unroll
        for (int i = 0; i < 4; ++i) {
            const int r = grp * 4 + i;
            const float4 v4 = *(const float4*)(lb + r * 64 + (((t & 15) ^ (r & 15)) * 4));
#pragma unroll
            for (int qq = 0; qq < 4; ++qq) {
                acc[qq].x = fmaf(pa[qq][i], v4.x, acc[qq].x);
                acc[qq].y = fmaf(pa[qq][i], v4.y, acc[qq].y);
                acc[qq].z = fmaf(pa[qq][i], v4.z, acc[qq].z);
                acc[qq].w = fmaf(pa[qq][i], v4.w, acc[qq].w);
            }
        }
    }
    // reduce over the 16 l-groups, one query at a time
#pragma unroll
    for (int qq = 0; qq < 4; ++qq) {
        __syncthreads();
        *(float4*)&pvred[grp][dq4] = acc[qq];
        __syncthreads();
        if (t < DD) {
            float s = 0.f;
#pragma unroll
            for (int u = 0; u < 16; ++u) s += pvred[u][t];
            const int prow = bh * NUMQ + qg * 4 + qq;
            part_pv[((size_t)prow * NLS + ls) * DD + t] = s;
        }
    }
}

// ---------------- K4b: attn finalize — one block per (bh,q) row -------------
__global__ __launch_bounds__(256) void attn_fin_kernel(
    const float* __restrict__ part_m, const float* __restrict__ part_s,
    const float* __restrict__ part_pv, float* __restrict__ attn_out,
    float* __restrict__ out_sel) {
    const int row = blockIdx.x;          // bh*NUMQ + q
    const int t = threadIdx.x;
    float m0 = part_m[row * NLS + 0], m1 = part_m[row * NLS + 1];
    float m2 = part_m[row * NLS + 2], m3 = part_m[row * NLS + 3];
    float M = fmaxf(fmaxf(m0, m1), fmaxf(m2, m3));
    float f[NLS];
    f[0] = __expf(m0 - M); f[1] = __expf(m1 - M);
    f[2] = __expf(m2 - M); f[3] = __expf(m3 - M);
    float T = part_s[row * NLS + 0] * f[0] + part_s[row * NLS + 1] * f[1]
            + part_s[row * NLS + 2] * f[2] + part_s[row * NLS + 3] * f[3];
    const float inv = 1.0f / T;
    float* arow = attn_out + (size_t)row * LL;
    {
        float4 v0 = *(const float4*)&arow[4 * t];
        float4 v1 = *(const float4*)&arow[1024 + 4 * t];
        const float g0 = f[(4 * t) >> 9] * inv;
        const float g1 = f[(1024 + 4 * t) >> 9] * inv;
        v0.x *= g0; v0.y *= g0; v0.z *= g0; v0.w *= g0;
        v1.x *= g1; v1.y *= g1; v1.z *= g1; v1.w *= g1;
        *(float4*)&arow[4 * t] = v0;
        *(float4*)&arow[1024 + 4 * t] = v1;
    }
    if (t < DD) {
        float s = part_pv[((size_t)row * NLS + 0) * DD + t] * f[0]
                + part_pv[((size_t)row * NLS + 1) * DD + t] * f[1]
                + part_pv[((size_t)row * NLS + 2) * DD + t] * f[2]
                + part_pv[((size_t)row * NLS + 3) * DD + t] * f[3];
        out_sel[(size_t)row * DD + t] = s * inv;
    }
}

// ---------------- K5: v_mean, two-stage ------------------------------------
__global__ __launch_bounds__(256) void vmean1_kernel(const float* __restrict__ vp2,
                                                     float* __restrict__ partial) {
    __shared__ float pv[256];
    const int t = threadIdx.x;
    const int chunk = blockIdx.x & 31;
    const int bh = blockIdx.x >> 5;
    const int d = t & 63, g = t >> 6;
    const int l0 = chunk * 64;
    float acc = 0.f;
    for (int l = l0 + g; l < l0 + 64; l += 4)
        acc += vp2[((size_t)bh * LL + l) * DD + d];
    pv[t] = acc;
    __syncthreads();
    if (t < 64)
        partial[(size_t)blockIdx.x * 64 + t] = pv[t] + pv[64 + t] + pv[128 + t] + pv[192 + t];
}

__global__ __launch_bounds__(64) void vmean2_kernel(const float* __restrict__ partial,
                                                    float* __restrict__ v_mean) {
    const int bh = blockIdx.x;
    const int t = threadIdx.x;
    float s = 0.f;
    for (int c = 0; c < 32; ++c)
        s += partial[((size_t)bh * 32 + c) * 64 + t];
    v_mean[bh * 64 + t] = s * (1.0f / LL);
}

// ---------------- K6: scatter + residual + LayerNorm ------------------------
__global__ __launch_bounds__(512) void final_kernel(const float* __restrict__ q_in,
                                                    const int* __restrict__ sel_pos,
                                                    const float* __restrict__ out_sel,
                                                    const float* __restrict__ v_mean,
                                                    const float* __restrict__ gamma,
                                                    const float* __restrict__ beta,
                                                    float* __restrict__ yout) {
    __shared__ float wred[8];
    const int j = threadIdx.x;
    const int lane = j & 63, wv = j >> 6;
    const int tok = blockIdx.x;          // b*L + l
    const int b = tok >> 11;
    const int l = tok & (LL - 1);
    const int h = wv, d = lane;
    const int bh = b * HH + h;
    const int p = sel_pos[(size_t)bh * LL + l];
    float val = (p >= 0) ? out_sel[((size_t)bh * NUMQ + p) * DD + d]
                         : v_mean[bh * DD + d];
    float y = val + q_in[(size_t)tok * DMM + j];
    float s = y;
#pragma unroll
    for (int off = 32; off > 0; off >>= 1) s += __shfl_xor(s, off, 64);
    if (lane == 0) wred[wv] = s;
    __syncthreads();
    float tot = 0.f;
#pragma unroll
    for (int u = 0; u < 8; ++u) tot += wred[u];
    float mu = tot * (1.0f / DMM);
    __syncthreads();
    float dv = y - mu;
    float s2 = dv * dv;
#pragma unroll
    for (int off = 32; off > 0; off >>= 1) s2 += __shfl_xor(s2, off, 64);
    if (lane == 0) wred[wv] = s2;
    __syncthreads();
    float tot2 = 0.f;
#pragma unroll
    for (int u = 0; u < 8; ++u) tot2 += wred[u];
    float var = tot2 * (1.0f / DMM);
    float yn = dv * rsqrtf(var + LNEPS) * gamma[j] + beta[j];
    yout[(size_t)tok * DMM + j] = yn;
}

extern "C" void kernel_launch(void* const* d_in, const int* in_sizes, int n_in,
                              void* d_out, int out_size, void* d_ws, size_t ws_size,
                              hipStream_t stream) {
    const float* q     = (const float*)d_in[0];
    const float* k     = (const float*)d_in[1];
    const float* v     = (const float*)d_in[2];
    const float* Wq    = (const float*)d_in[3];
    const float* bq    = (const float*)d_in[4];
    const float* Wk    = (const float*)d_in[5];
    const float* bk    = (const float*)d_in[6];
    const float* Wv    = (const float*)d_in[7];
    const float* bv    = (const float*)d_in[8];
    const float* gamma = (const float*)d_in[9];
    const float* beta  = (const float*)d_in[10];
    const int*   rnd   = (const int*)d_in[11];

    float* ws = (float*)d_ws;
    const size_t proj_sz = (size_t)BB * HH * LL * DD;      // = B*L*DM elements
    float* qp2     = ws;
    float* kp2     = qp2 + proj_sz;
    float* vp2     = kp2 + proj_sz;
    float* measure = vp2 + proj_sz;                        // B*H*L
    float* out_sel = measure + (size_t)BB * HH * LL;       // B*H*NUMQ*D
    float* v_mean  = out_sel + (size_t)BB * HH * NUMQ * DD;// B*H*D
    float* partial = v_mean + (size_t)BB * HH * DD;        // B*H*32*64
    float* part_m  = partial + (size_t)BB * HH * 32 * 64;  // 640*4
    float* part_s  = part_m + (size_t)BB * HH * NUMQ * NLS;
    float* part_pv = part_s + (size_t)BB * HH * NUMQ * NLS;// 640*4*64
    int*   q_idx   = (int*)(part_pv + (size_t)BB * HH * NUMQ * NLS * DD);
    int*   sel_pos = q_idx + BB * HH * NUMQ;               // B*H*L
    ushort_t* Xh  = (ushort_t*)(sel_pos + BB * HH * LL);
    ushort_t* Xl  = Xh + 3 * proj_sz;
    ushort_t* Wht = Xl + 3 * proj_sz;
    ushort_t* Wlt = Wht + 3 * (size_t)DMM * DMM;

    float* yn_out   = (float*)d_out;
    float* attn_out = yn_out + (size_t)BB * LL * DMM;

    convert_x_kernel<<<dim3(BB * LL * DMM / (256 * 8), 3), 256, 0, stream>>>(q, k, v, Xh, Xl);
    convert_w_kernel<<<dim3(DMM / 64, DMM / 64, 3), 256, 0, stream>>>(Wq, Wk, Wv, Wht, Wlt);
    proj_mfma_kernel<<<dim3(BB * LL / 64, DMM / 64, 3), 256, 0, stream>>>(
        Xh, Xl, Wht, Wlt, bq, bk, bv, qp2, kp2, vp2);
    vmean1_kernel<<<BB * HH * 32, 256, 0, stream>>>(vp2, partial);
    vmean2_kernel<<<BB * HH, 64, 0, stream>>>(partial, v_mean);
    measure_kernel<<<dim3(BB * HH, LL / 16), 256, 0, stream>>>(qp2, kp2, rnd, measure);
    topk_kernel<<<BB * HH, 256, 0, stream>>>(measure, q_idx, sel_pos);
    attn_part_kernel<<<dim3(BB * HH, NUMQ / 4, NLS), 256, 0, stream>>>(
        qp2, kp2, vp2, q_idx, attn_out, part_m, part_s, part_pv);
    attn_fin_kernel<<<BB * HH * NUMQ, 256, 0, stream>>>(
        part_m, part_s, part_pv, attn_out, out_sel);
    final_kernel<<<BB * LL, 512, 0, stream>>>(q, sel_pos, out_sel, v_mean, gamma, beta, yn_out);
}

// Round 9
// 217.146 us; speedup vs baseline: 1.1920x; 1.0448x over previous
//
#include <hip/hip_runtime.h>
#include <math.h>

#define BB 2
#define LL 2048
#define DMM 512
#define HH 8
#define DD 64
#define NUMK 40
#define NUMQ 40
#define LNEPS 1e-5f
#define LSEG 512
#define NLS 4

typedef unsigned short ushort_t;
typedef __attribute__((ext_vector_type(8))) short bf16x8;
typedef __attribute__((ext_vector_type(4))) float f32x4;

// ---- bf16 helpers (RNE) ----
__device__ inline ushort_t f2bf(float x) {
    union { float f; unsigned int u; } v; v.f = x;
    unsigned int r = v.u + 0x7fffu + ((v.u >> 16) & 1u);
    return (ushort_t)(r >> 16);
}
__device__ inline float bf2f(ushort_t h) {
    union { unsigned int u; float f; } v; v.u = ((unsigned int)h) << 16;
    return v.f;
}

// ---------------- K0a: convert X (q,k,v) -> hi/lo bf16 ----------------------
__global__ __launch_bounds__(256) void convert_x_kernel(
    const float* __restrict__ q, const float* __restrict__ k, const float* __restrict__ v,
    ushort_t* __restrict__ Xh, ushort_t* __restrict__ Xl) {
    const size_t plane = (size_t)BB * LL * DMM;
    const float* X = (blockIdx.y == 0) ? q : (blockIdx.y == 1) ? k : v;
    ushort_t* xh = Xh + plane * blockIdx.y;
    ushort_t* xl = Xl + plane * blockIdx.y;
    const size_t base = ((size_t)blockIdx.x * 256 + threadIdx.x) * 8;
    float4 a = *(const float4*)(X + base);
    float4 b = *(const float4*)(X + base + 4);
    float xs[8] = {a.x, a.y, a.z, a.w, b.x, b.y, b.z, b.w};
    unsigned int hp[4], lp[4];
#pragma unroll
    for (int j = 0; j < 4; ++j) {
        ushort_t h0 = f2bf(xs[2 * j]),     h1 = f2bf(xs[2 * j + 1]);
        ushort_t l0 = f2bf(xs[2 * j] - bf2f(h0));
        ushort_t l1 = f2bf(xs[2 * j + 1] - bf2f(h1));
        hp[j] = (unsigned int)h0 | ((unsigned int)h1 << 16);
        lp[j] = (unsigned int)l0 | ((unsigned int)l1 << 16);
    }
    *(uint4*)(xh + base) = make_uint4(hp[0], hp[1], hp[2], hp[3]);
    *(uint4*)(xl + base) = make_uint4(lp[0], lp[1], lp[2], lp[3]);
}

// ---------------- K0b: convert + transpose W -> Wt[n][k] hi/lo bf16 ---------
__global__ __launch_bounds__(256) void convert_w_kernel(
    const float* __restrict__ Wq, const float* __restrict__ Wk, const float* __restrict__ Wv,
    ushort_t* __restrict__ Wht, ushort_t* __restrict__ Wlt) {
    __shared__ float tile[64][65];
    const size_t plane = (size_t)DMM * DMM;
    const float* W = (blockIdx.z == 0) ? Wq : (blockIdx.z == 1) ? Wk : Wv;
    ushort_t* wht = Wht + plane * blockIdx.z;
    ushort_t* wlt = Wlt + plane * blockIdx.z;
    const int n0 = blockIdx.x * 64, k0 = blockIdx.y * 64;
    const int t = threadIdx.x;
    const int d = t & 63, g = t >> 6;
    for (int rr = g; rr < 64; rr += 4)
        tile[rr][d] = W[(size_t)(k0 + rr) * DMM + n0 + d];
    __syncthreads();
    for (int cc = g; cc < 64; cc += 4) {
        float x = tile[d][cc];            // = W[k0+d][n0+cc]
        ushort_t hi = f2bf(x);
        ushort_t lo = f2bf(x - bf2f(hi));
        wht[(size_t)(n0 + cc) * DMM + k0 + d] = hi;
        wlt[(size_t)(n0 + cc) * DMM + k0 + d] = lo;
    }
}

// ---------------- K1: split-bf16 MFMA projection GEMM (3-term) --------------
__device__ inline void stage_one(const ushort_t* __restrict__ g, ushort_t* lbuf,
                                 int r0, int lane, int k0) {
    const int r = r0 + (lane >> 3);
    const int c = (lane & 7) ^ (r & 7);
    const ushort_t* gp = g + (size_t)r * DMM + k0 + c * 8;
    __builtin_amdgcn_global_load_lds(
        (const __attribute__((address_space(1))) unsigned int*)gp,
        (__attribute__((address_space(3))) unsigned int*)(lbuf + (size_t)r0 * 64),
        16, 0, 0);
}
__device__ inline bf16x8 frag_ld(const ushort_t* buf, int row, int c) {
    const int idx = row * 8 + (c ^ (row & 7));
    return *(const bf16x8*)(buf + idx * 8);
}

__global__ __launch_bounds__(256) void proj_mfma_kernel(
    const ushort_t* __restrict__ Xh, const ushort_t* __restrict__ Xl,
    const ushort_t* __restrict__ Wht, const ushort_t* __restrict__ Wlt,
    const float* __restrict__ bq, const float* __restrict__ bk, const float* __restrict__ bv,
    float* __restrict__ Oq, float* __restrict__ Ok, float* __restrict__ Ov) {
    const int z = blockIdx.z;
    const size_t xplane = (size_t)BB * LL * DMM;
    const size_t wplane = (size_t)DMM * DMM;
    const ushort_t* ah_g = Xh + xplane * z;
    const ushort_t* al_g = Xl + xplane * z;
    const ushort_t* bh_g = Wht + wplane * z;
    const ushort_t* bl_g = Wlt + wplane * z;
    const float* bias = (z == 0) ? bq : (z == 1) ? bk : bv;
    float* Out = (z == 0) ? Oq : (z == 1) ? Ok : Ov;

    __shared__ __align__(16) ushort_t bufAh[64 * 64];
    __shared__ __align__(16) ushort_t bufAl[64 * 64];
    __shared__ __align__(16) ushort_t bufBh[64 * 64];
    __shared__ __align__(16) ushort_t bufBl[64 * 64];

    const int t = threadIdx.x;
    const int lane = t & 63, w = t >> 6;
    const int wm = (w & 1) * 32, wn = (w >> 1) * 32;
    const int m0 = blockIdx.x * 64, j0 = blockIdx.y * 64;

    const ushort_t* A_h = ah_g + (size_t)m0 * DMM;
    const ushort_t* A_l = al_g + (size_t)m0 * DMM;
    const ushort_t* B_h = bh_g + (size_t)j0 * DMM;
    const ushort_t* B_l = bl_g + (size_t)j0 * DMM;

    f32x4 acc[2][2];
#pragma unroll
    for (int i = 0; i < 2; ++i)
#pragma unroll
        for (int j = 0; j < 2; ++j) acc[i][j] = (f32x4){0.f, 0.f, 0.f, 0.f};

    for (int ch = 0; ch < 8; ++ch) {
        const int k0 = ch * 64;
#pragma unroll
        for (int i = 0; i < 2; ++i) {
            const int r0 = (w * 2 + i) * 8;
            stage_one(A_h, bufAh, r0, lane, k0);
            stage_one(A_l, bufAl, r0, lane, k0);
            stage_one(B_h, bufBh, r0, lane, k0);
            stage_one(B_l, bufBl, r0, lane, k0);
        }
        __syncthreads();
#pragma unroll
        for (int ks = 0; ks < 2; ++ks) {
            const int cc = ks * 4 + (lane >> 4);
            bf16x8 fah[2], fal[2], fbh[2], fbl[2];
#pragma unroll
            for (int tm = 0; tm < 2; ++tm) {
                const int row = wm + tm * 16 + (lane & 15);
                fah[tm] = frag_ld(bufAh, row, cc);
                fal[tm] = frag_ld(bufAl, row, cc);
            }
#pragma unroll
            for (int tn = 0; tn < 2; ++tn) {
                const int row = wn + tn * 16 + (lane & 15);
                fbh[tn] = frag_ld(bufBh, row, cc);
                fbl[tn] = frag_ld(bufBl, row, cc);
            }
#pragma unroll
            for (int tm = 0; tm < 2; ++tm)
#pragma unroll
                for (int tn = 0; tn < 2; ++tn) {
                    acc[tm][tn] = __builtin_amdgcn_mfma_f32_16x16x32_bf16(fah[tm], fbh[tn], acc[tm][tn], 0, 0, 0);
                    acc[tm][tn] = __builtin_amdgcn_mfma_f32_16x16x32_bf16(fal[tm], fbh[tn], acc[tm][tn], 0, 0, 0);
                    acc[tm][tn] = __builtin_amdgcn_mfma_f32_16x16x32_bf16(fah[tm], fbl[tn], acc[tm][tn], 0, 0, 0);
                }
        }
        __syncthreads();
    }

#pragma unroll
    for (int tn = 0; tn < 2; ++tn) {
        const int gn = j0 + wn + tn * 16 + (lane & 15);
        const float bvv = bias[gn];
        const int h = gn >> 6, d = gn & 63;
#pragma unroll
        for (int tm = 0; tm < 2; ++tm) {
#pragma unroll
            for (int reg = 0; reg < 4; ++reg) {
                const int gm = m0 + wm + tm * 16 + (lane >> 4) * 4 + reg;
                const int b = gm >> 11, l = gm & (LL - 1);
                Out[(((size_t)(b * HH + h)) * LL + l) * DD + d] = acc[tm][tn][reg] + bvv;
            }
        }
    }
}

// ---------------- K2: measure — 4 queries/wave, 16 lanes each ---------------
__global__ __launch_bounds__(256) void measure_kernel(const float* __restrict__ qp2,
                                                      const float* __restrict__ kp2,
                                                      const int* __restrict__ rnd,
                                                      float* __restrict__ measure) {
    const int t = threadIdx.x;
    const int lane = t & 63;
    const int wv = t >> 6;
    const int g = lane >> 4;
    const int dq = (lane & 15) * 4;
    const int bh = blockIdx.x;
    const int i = blockIdx.y * 16 + wv * 4 + g;
    const float4 qv = *(const float4*)(qp2 + ((size_t)bh * LL + i) * DD + dq);
    const float* kbase = kp2 + (size_t)bh * LL * DD;
    const int* rp = rnd + i * NUMK;
    float mx = -INFINITY, sm = 0.f;
#pragma unroll 8
    for (int j = 0; j < NUMK; ++j) {
        const int row = rp[j];
        const float4 kv = *(const float4*)(kbase + (size_t)row * DD + dq);
        float p = kv.x * qv.x;
        p = fmaf(kv.y, qv.y, p); p = fmaf(kv.z, qv.z, p); p = fmaf(kv.w, qv.w, p);
        p += __shfl_xor(p, 1, 64);
        p += __shfl_xor(p, 2, 64);
        p += __shfl_xor(p, 4, 64);
        p += __shfl_xor(p, 8, 64);
        mx = fmaxf(mx, p);
        sm += p;
    }
    if ((lane & 15) == 0) measure[(size_t)bh * LL + i] = mx - sm * (1.0f / LL);
}

// ---------------- K3: top-40 via 4-round byte-radix refinement --------------
// One block per bh. Finds exact 32-bit key of the 40th-largest element, then
// ranks the <=~48 candidates exactly (desc value, ties lower index) —
// reproduces lax.top_k semantics.
__global__ __launch_bounds__(256) void topk_kernel(const float* __restrict__ measure,
                                                   int* __restrict__ q_idx,
                                                   int* __restrict__ sel_pos) {
    __shared__ unsigned int keys[LL];      // 8 KB
    __shared__ int hist[256];
    __shared__ unsigned int prefix_sh;
    __shared__ int need_sh;
    __shared__ unsigned int cval[256];
    __shared__ int cidx[256];
    __shared__ int cnt;
    const int t = threadIdx.x;
    const int bh = blockIdx.x;
    for (int i = t; i < LL; i += 256) {
        const float f = measure[(size_t)bh * LL + i];
        unsigned int u = __float_as_uint(f);
        // order-preserving: descending float == descending uint key
        keys[i] = (u & 0x80000000u) ? ~u : (u | 0x80000000u);
        sel_pos[(size_t)bh * LL + i] = -1;
    }
    if (t == 0) { prefix_sh = 0u; need_sh = NUMQ; cnt = 0; }
    __syncthreads();

    // 4 rounds: byte 3 -> byte 0
    for (int round = 0; round < 4; ++round) {
        const int shift = 24 - round * 8;
        hist[t] = 0;
        __syncthreads();
        const unsigned int pref = prefix_sh;
        const unsigned int mask = (round == 0) ? 0u : (0xFFFFFFFFu << (shift + 8));
        for (int i = t; i < LL; i += 256) {
            const unsigned int key = keys[i];
            if ((key & mask) == pref)
                atomicAdd(&hist[(key >> shift) & 0xFF], 1);
        }
        __syncthreads();
        if (t == 0) {
            const int need = need_sh;
            int acc = 0;
            int v = 255;
            for (; v > 0; --v) {
                if (acc + hist[v] >= need) break;
                acc += hist[v];
            }
            need_sh = need - acc;                    // rank within chosen byte-bin
            prefix_sh = pref | ((unsigned int)v << shift);
        }
        __syncthreads();
    }
    const unsigned int K40 = prefix_sh;   // exact key of the 40th-largest

    // collect all candidates >= K40 (#{>K40} <= 39, plus exact dups of K40)
    for (int i = t; i < LL; i += 256) {
        if (keys[i] >= K40) {
            int p = atomicAdd(&cnt, 1);
            if (p < 256) { cval[p] = keys[i]; cidx[p] = i; }
        }
    }
    __syncthreads();
    int M = cnt; if (M > 256) M = 256;
    // exact rank among candidates
    for (int i = t; i < M; i += 256) {
        const unsigned int ki = cval[i];
        const int ii = cidx[i];
        int r = 0;
        for (int j = 0; j < M; ++j) {
            const unsigned int kj = cval[j];
            r += (kj > ki || (kj == ki && cidx[j] < ii)) ? 1 : 0;
        }
        if (r < NUMQ) {
            q_idx[bh * NUMQ + r] = ii;
            sel_pos[(size_t)bh * LL + ii] = r;
        }
    }
}

// ---------------- K4a: attn partial, LDS-staged -----------------------------
__global__ __launch_bounds__(256) void attn_part_kernel(
    const float* __restrict__ qp2, const float* __restrict__ kp2,
    const float* __restrict__ vp2, const int* __restrict__ q_idx,
    float* __restrict__ attn_out, float* __restrict__ part_m,
    float* __restrict__ part_s, float* __restrict__ part_pv) {
    __shared__ __align__(16) float buf[2][64 * 64];   // 2 x 16KB
    __shared__ __align__(16) float sc[4][LSEG];       // 8KB
    __shared__ float pvred[16][68];
    const int t = threadIdx.x;
    const int lane = t & 63, w = t >> 6;
    const int bh = blockIdx.x;
    const int qg = blockIdx.y;      // 0..9
    const int ls = blockIdx.z;      // 0..3
    const int l0 = ls * LSEG;
    const int dseg = lane >> 4;     // 0..3: 16-float slice of d
    const int kk = lane & 15;

    float qrf[4][16];
#pragma unroll
    for (int qq = 0; qq < 4; ++qq) {
        const int qi = q_idx[bh * NUMQ + qg * 4 + qq];
        const float* qrow = qp2 + ((size_t)bh * LL + qi) * DD + dseg * 16;
#pragma unroll
        for (int j = 0; j < 4; ++j) {
            float4 v = *(const float4*)(qrow + j * 4);
            qrf[qq][j * 4 + 0] = v.x * 0.125f;
            qrf[qq][j * 4 + 1] = v.y * 0.125f;
            qrf[qq][j * 4 + 2] = v.z * 0.125f;
            qrf[qq][j * 4 + 3] = v.w * 0.125f;
        }
    }

    const float* kseg = kp2 + ((size_t)bh * LL + l0) * DD;
    const float* vseg = vp2 + ((size_t)bh * LL + l0) * DD;

    auto stage = [&](const float* gsrc, float* lb) {
#pragma unroll
        for (int i = 0; i < 4; ++i) {
            const int instr = w * 4 + i;
            const int r = instr * 4 + (lane >> 4);
            const int cg = (lane & 15) ^ (r & 15);
            const float* gp = gsrc + (size_t)r * DD + cg * 4;
            __builtin_amdgcn_global_load_lds(
                (const __attribute__((address_space(1))) unsigned int*)gp,
                (__attribute__((address_space(3))) unsigned int*)(lb + instr * 256),
                16, 0, 0);
        }
    };

    // ---- Loop 1: QK^T ----
    stage(kseg, buf[0]);
    const int krow = w * 16 + kk;
    for (int c = 0; c < 8; ++c) {
        __syncthreads();
        if (c < 7) stage(kseg + (size_t)(c + 1) * 64 * DD, buf[(c + 1) & 1]);
        const float* lb = buf[c & 1];
        float dot[4] = {0.f, 0.f, 0.f, 0.f};
#pragma unroll
        for (int j = 0; j < 4; ++j) {
            const int cg = dseg * 4 + j;
            const float4 k4 = *(const float4*)(lb + krow * 64 + ((cg ^ (krow & 15)) * 4));
            const float kf[4] = {k4.x, k4.y, k4.z, k4.w};
#pragma unroll
            for (int qq = 0; qq < 4; ++qq)
#pragma unroll
                for (int m = 0; m < 4; ++m)
                    dot[qq] = fmaf(qrf[qq][j * 4 + m], kf[m], dot[qq]);
        }
#pragma unroll
        for (int qq = 0; qq < 4; ++qq) {
            dot[qq] += __shfl_xor(dot[qq], 16, 64);
            dot[qq] += __shfl_xor(dot[qq], 32, 64);
        }
        const float sel = (dseg == 0) ? dot[0] : (dseg == 1) ? dot[1]
                        : (dseg == 2) ? dot[2] : dot[3];
        sc[dseg][c * 64 + krow] = sel;
    }
    stage(vseg, buf[0]);
    __syncthreads();

    // ---- softmax partial: wave w handles query qq = w ----
    const int row = bh * NUMQ + qg * 4 + w;
    {
        float* srow = sc[w];
        float4 v0 = *(float4*)(srow + lane * 8);
        float4 v1 = *(float4*)(srow + lane * 8 + 4);
        float m = fmaxf(fmaxf(fmaxf(v0.x, v0.y), fmaxf(v0.z, v0.w)),
                        fmaxf(fmaxf(v1.x, v1.y), fmaxf(v1.z, v1.w)));
#pragma unroll
        for (int off = 32; off > 0; off >>= 1) m = fmaxf(m, __shfl_xor(m, off, 64));
        v0.x = __expf(v0.x - m); v0.y = __expf(v0.y - m);
        v0.z = __expf(v0.z - m); v0.w = __expf(v0.w - m);
        v1.x = __expf(v1.x - m); v1.y = __expf(v1.y - m);
        v1.z = __expf(v1.z - m); v1.w = __expf(v1.w - m);
        *(float4*)(srow + lane * 8) = v0;
        *(float4*)(srow + lane * 8 + 4) = v1;
        float* arow = attn_out + (size_t)row * LL + l0;
        *(float4*)(arow + lane * 8) = v0;
        *(float4*)(arow + lane * 8 + 4) = v1;
        float s = (v0.x + v0.y + v0.z + v0.w) + (v1.x + v1.y + v1.z + v1.w);
#pragma unroll
        for (int off = 32; off > 0; off >>= 1) s += __shfl_xor(s, off, 64);
        if (lane == 0) {
            part_m[row * NLS + ls] = m;
            part_s[row * NLS + ls] = s;
        }
    }

    // ---- Loop 2: PV ----
    const int dq4 = (t & 15) * 4;
    const int grp = t >> 4;
    float4 acc[4];
#pragma unroll
    for (int qq = 0; qq < 4; ++qq) acc[qq] = make_float4(0.f, 0.f, 0.f, 0.f);
    for (int c = 0; c < 8; ++c) {
        __syncthreads();
        if (c < 7) stage(vseg + (size_t)(c + 1) * 64 * DD, buf[(c + 1) & 1]);
        const float* lb = buf[c & 1];
        float pa[4][4];
#pragma unroll
        for (int qq = 0; qq < 4; ++qq)
            *(float4*)&pa[qq][0] = *(const float4*)&sc[qq][c * 64 + grp * 4];
#pragma unroll
        for (int i = 0; i < 4; ++i) {
            const int r = grp * 4 + i;
            const float4 v4 = *(const float4*)(lb + r * 64 + (((t & 15) ^ (r & 15)) * 4));
#pragma unroll
            for (int qq = 0; qq < 4; ++qq) {
                acc[qq].x = fmaf(pa[qq][i], v4.x, acc[qq].x);
                acc[qq].y = fmaf(pa[qq][i], v4.y, acc[qq].y);
                acc[qq].z = fmaf(pa[qq][i], v4.z, acc[qq].z);
                acc[qq].w = fmaf(pa[qq][i], v4.w, acc[qq].w);
            }
        }
    }
#pragma unroll
    for (int qq = 0; qq < 4; ++qq) {
        __syncthreads();
        *(float4*)&pvred[grp][dq4] = acc[qq];
        __syncthreads();
        if (t < DD) {
            float s = 0.f;
#pragma unroll
            for (int u = 0; u < 16; ++u) s += pvred[u][t];
            const int prow = bh * NUMQ + qg * 4 + qq;
            part_pv[((size_t)prow * NLS + ls) * DD + t] = s;
        }
    }
}

// ---------------- K4b: attn finalize — one block per (bh,q) row -------------
__global__ __launch_bounds__(256) void attn_fin_kernel(
    const float* __restrict__ part_m, const float* __restrict__ part_s,
    const float* __restrict__ part_pv, float* __restrict__ attn_out,
    float* __restrict__ out_sel) {
    const int row = blockIdx.x;          // bh*NUMQ + q
    const int t = threadIdx.x;
    float m0 = part_m[row * NLS + 0], m1 = part_m[row * NLS + 1];
    float m2 = part_m[row * NLS + 2], m3 = part_m[row * NLS + 3];
    float M = fmaxf(fmaxf(m0, m1), fmaxf(m2, m3));
    float f[NLS];
    f[0] = __expf(m0 - M); f[1] = __expf(m1 - M);
    f[2] = __expf(m2 - M); f[3] = __expf(m3 - M);
    float T = part_s[row * NLS + 0] * f[0] + part_s[row * NLS + 1] * f[1]
            + part_s[row * NLS + 2] * f[2] + part_s[row * NLS + 3] * f[3];
    const float inv = 1.0f / T;
    float* arow = attn_out + (size_t)row * LL;
    {
        float4 v0 = *(const float4*)&arow[4 * t];
        float4 v1 = *(const float4*)&arow[1024 + 4 * t];
        const float g0 = f[(4 * t) >> 9] * inv;
        const float g1 = f[(1024 + 4 * t) >> 9] * inv;
        v0.x *= g0; v0.y *= g0; v0.z *= g0; v0.w *= g0;
        v1.x *= g1; v1.y *= g1; v1.z *= g1; v1.w *= g1;
        *(float4*)&arow[4 * t] = v0;
        *(float4*)&arow[1024 + 4 * t] = v1;
    }
    if (t < DD) {
        float s = part_pv[((size_t)row * NLS + 0) * DD + t] * f[0]
                + part_pv[((size_t)row * NLS + 1) * DD + t] * f[1]
                + part_pv[((size_t)row * NLS + 2) * DD + t] * f[2]
                + part_pv[((size_t)row * NLS + 3) * DD + t] * f[3];
        out_sel[(size_t)row * DD + t] = s * inv;
    }
}

// ---------------- K5: v_mean, two-stage ------------------------------------
__global__ __launch_bounds__(256) void vmean1_kernel(const float* __restrict__ vp2,
                                                     float* __restrict__ partial) {
    __shared__ float pv[256];
    const int t = threadIdx.x;
    const int chunk = blockIdx.x & 31;
    const int bh = blockIdx.x >> 5;
    const int d = t & 63, g = t >> 6;
    const int l0 = chunk * 64;
    float acc = 0.f;
    for (int l = l0 + g; l < l0 + 64; l += 4)
        acc += vp2[((size_t)bh * LL + l) * DD + d];
    pv[t] = acc;
    __syncthreads();
    if (t < 64)
        partial[(size_t)blockIdx.x * 64 + t] = pv[t] + pv[64 + t] + pv[128 + t] + pv[192 + t];
}

__global__ __launch_bounds__(64) void vmean2_kernel(const float* __restrict__ partial,
                                                    float* __restrict__ v_mean) {
    const int bh = blockIdx.x;
    const int t = threadIdx.x;
    float s = 0.f;
    for (int c = 0; c < 32; ++c)
        s += partial[((size_t)bh * 32 + c) * 64 + t];
    v_mean[bh * 64 + t] = s * (1.0f / LL);
}

// ---------------- K6: scatter + residual + LayerNorm ------------------------
__global__ __launch_bounds__(512) void final_kernel(const float* __restrict__ q_in,
                                                    const int* __restrict__ sel_pos,
                                                    const float* __restrict__ out_sel,
                                                    const float* __restrict__ v_mean,
                                                    const float* __restrict__ gamma,
                                                    const float* __restrict__ beta,
                                                    float* __restrict__ yout) {
    __shared__ float wred[8];
    const int j = threadIdx.x;
    const int lane = j & 63, wv = j >> 6;
    const int tok = blockIdx.x;          // b*L + l
    const int b = tok >> 11;
    const int l = tok & (LL - 1);
    const int h = wv, d = lane;
    const int bh = b * HH + h;
    const int p = sel_pos[(size_t)bh * LL + l];
    float val = (p >= 0) ? out_sel[((size_t)bh * NUMQ + p) * DD + d]
                         : v_mean[bh * DD + d];
    float y = val + q_in[(size_t)tok * DMM + j];
    float s = y;
#pragma unroll
    for (int off = 32; off > 0; off >>= 1) s += __shfl_xor(s, off, 64);
    if (lane == 0) wred[wv] = s;
    __syncthreads();
    float tot = 0.f;
#pragma unroll
    for (int u = 0; u < 8; ++u) tot += wred[u];
    float mu = tot * (1.0f / DMM);
    __syncthreads();
    float dv = y - mu;
    float s2 = dv * dv;
#pragma unroll
    for (int off = 32; off > 0; off >>= 1) s2 += __shfl_xor(s2, off, 64);
    if (lane == 0) wred[wv] = s2;
    __syncthreads();
    float tot2 = 0.f;
#pragma unroll
    for (int u = 0; u < 8; ++u) tot2 += wred[u];
    float var = tot2 * (1.0f / DMM);
    float yn = dv * rsqrtf(var + LNEPS) * gamma[j] + beta[j];
    yout[(size_t)tok * DMM + j] = yn;
}

extern "C" void kernel_launch(void* const* d_in, const int* in_sizes, int n_in,
                              void* d_out, int out_size, void* d_ws, size_t ws_size,
                              hipStream_t stream) {
    const float* q     = (const float*)d_in[0];
    const float* k     = (const float*)d_in[1];
    const float* v     = (const float*)d_in[2];
    const float* Wq    = (const float*)d_in[3];
    const float* bq    = (const float*)d_in[4];
    const float* Wk    = (const float*)d_in[5];
    const float* bk    = (const float*)d_in[6];
    const float* Wv    = (const float*)d_in[7];
    const float* bv    = (const float*)d_in[8];
    const float* gamma = (const float*)d_in[9];
    const float* beta  = (const float*)d_in[10];
    const int*   rnd   = (const int*)d_in[11];

    float* ws = (float*)d_ws;
    const size_t proj_sz = (size_t)BB * HH * LL * DD;      // = B*L*DM elements
    float* qp2     = ws;
    float* kp2     = qp2 + proj_sz;
    float* vp2     = kp2 + proj_sz;
    float* measure = vp2 + proj_sz;                        // B*H*L
    float* out_sel = measure + (size_t)BB * HH * LL;       // B*H*NUMQ*D
    float* v_mean  = out_sel + (size_t)BB * HH * NUMQ * DD;// B*H*D
    float* partial = v_mean + (size_t)BB * HH * DD;        // B*H*32*64
    float* part_m  = partial + (size_t)BB * HH * 32 * 64;  // 640*4
    float* part_s  = part_m + (size_t)BB * HH * NUMQ * NLS;
    float* part_pv = part_s + (size_t)BB * HH * NUMQ * NLS;// 640*4*64
    int*   q_idx   = (int*)(part_pv + (size_t)BB * HH * NUMQ * NLS * DD);
    int*   sel_pos = q_idx + BB * HH * NUMQ;               // B*H*L
    ushort_t* Xh  = (ushort_t*)(sel_pos + BB * HH * LL);
    ushort_t* Xl  = Xh + 3 * proj_sz;
    ushort_t* Wht = Xl + 3 * proj_sz;
    ushort_t* Wlt = Wht + 3 * (size_t)DMM * DMM;

    float* yn_out   = (float*)d_out;
    float* attn_out = yn_out + (size_t)BB * LL * DMM;

    convert_x_kernel<<<dim3(BB * LL * DMM / (256 * 8), 3), 256, 0, stream>>>(q, k, v, Xh, Xl);
    convert_w_kernel<<<dim3(DMM / 64, DMM / 64, 3), 256, 0, stream>>>(Wq, Wk, Wv, Wht, Wlt);
    proj_mfma_kernel<<<dim3(BB * LL / 64, DMM / 64, 3), 256, 0, stream>>>(
        Xh, Xl, Wht, Wlt, bq, bk, bv, qp2, kp2, vp2);
    vmean1_kernel<<<BB * HH * 32, 256, 0, stream>>>(vp2, partial);
    vmean2_kernel<<<BB * HH, 64, 0, stream>>>(partial, v_mean);
    measure_kernel<<<dim3(BB * HH, LL / 16), 256, 0, stream>>>(qp2, kp2, rnd, measure);
    topk_kernel<<<BB * HH, 256, 0, stream>>>(measure, q_idx, sel_pos);
    attn_part_kernel<<<dim3(BB * HH, NUMQ / 4, NLS), 256, 0, stream>>>(
        qp2, kp2, vp2, q_idx, attn_out, part_m, part_s, part_pv);
    attn_fin_kernel<<<BB * HH * NUMQ, 256, 0, stream>>>(
        part_m, part_s, part_pv, attn_out, out_sel);
    final_kernel<<<BB * LL, 512, 0, stream>>>(q, sel_pos, out_sel, v_mean, gamma, beta, yn_out);
}